// Round 14
// baseline (188.563 us; speedup 1.0000x reference)
//
#include <hip/hip_runtime.h>

typedef __attribute__((ext_vector_type(8))) short bf16x8;
typedef __attribute__((ext_vector_type(4))) float f32x4;
typedef __attribute__((ext_vector_type(2))) unsigned int u32x2;

#define NBLK 512
#define NTHR 512    // 8 waves; 1 block/CU (128 KB LDS)
#define NT   32     // 32-row tiles per block: 512*32*32 = 524288 rows
#define DOUT 128

__device__ __forceinline__ unsigned short bf_rne(float x) {
  unsigned u = __builtin_bit_cast(unsigned, x);
  return (unsigned short)((u + 0x7FFFu + ((u >> 16) & 1u)) >> 16);
}
// fp32 -> bf16 hi (truncate) + bf16 lo (RNE of residual); x ~ hi+lo to ~2^-15 rel
__device__ __forceinline__ void split2(float x, short& hi, short& lo) {
  unsigned u = __builtin_bit_cast(unsigned, x);
  float hf = __builtin_bit_cast(float, u & 0xFFFF0000u);
  hi = (short)(unsigned short)(u >> 16);
  lo = (short)bf_rne(x - hf);
}

// async global->LDS, 16B/lane, per-lane global src + wave-uniform LDS base
__device__ __forceinline__ void gll16(const float* g, char* l) {
  __builtin_amdgcn_global_load_lds(
      (const __attribute__((address_space(1))) unsigned int*)g,
      (__attribute__((address_space(3))) unsigned int*)l, 16, 0, 0);
}

// R14 = R13 dataflow with the LDS pipe fixed (R13: 1.05e7 conflicts, 2-barrier
// phase-lock -> LDS bursts serialized; 7840 cyc/iter vs ~5400 accounted).
//  1) ONE barrier/iter: SPLIT(t+1)->B16[r^1] has no dep on MFMA(t)<-B16[r];
//     merged region lets the compiler interleave them. vmcnt(4) counted, never 0.
//  2) SPLIT F-read: granules {v,v+16,v+32,v+48} (stride-256B) — 0 conflicts
//     (R13's 4-consecutive was stride-64B = 8-way).
//  3) B16 layout: row*512 + ((ks*64+chunk*16) ^ ((row&7)<<4)) (+h*8 on write).
//     All three patterns (DMA-linear F, b64 split-write, b128 frag-read)
//     enumerate to the wave64 inherent minimum, 0 conflicts.
// W masked/split in 64 VGPRs/wave (16 cols). (512,2): cap 128, body ~100.
__global__ __launch_bounds__(NTHR, 2)
void dagmm(const float* __restrict__ x0, const float* __restrict__ x1,
           const float* __restrict__ w0, const float* __restrict__ w1,
           const float* __restrict__ m0, const float* __restrict__ m1,
           float* __restrict__ out)
{
  __shared__ __align__(16) char L[131072];
  // F(r)  = r*32768          : fp32 tile [32 rows][1024 B], row-major (DMA dst)
  // B16(r)= 65536 + r*32768  : bf16 hi plane 16 KB (row*512), lo at +16384

  const int t   = threadIdx.x;
  const int l   = t & 63;
  const int w   = t >> 6;       // wave 0..7 -> owns output cols [w*16, w*16+16)
  const int l16 = l & 15;
  const int lq  = l >> 4;

  // ---------- W preamble: masked + hi/lo-split A-frags in VGPRs ----------
  bf16x8 bhi[8], blo[8];
  {
    const int col = w * 16 + l16;
#pragma unroll
    for (int ks = 0; ks < 8; ++ks) {
      const int k0 = ks * 32 + lq * 8;            // never straddles 128
      const float* wp = (k0 < 128) ? (w0 + col * 128 + k0) : (w1 + col * 128 + (k0 - 128));
      const float* mp = (k0 < 128) ? (m0 + col * 128 + k0) : (m1 + col * 128 + (k0 - 128));
      float4 wa = *(const float4*)wp, wb = *(const float4*)(wp + 4);
      float4 ma = *(const float4*)mp, mb = *(const float4*)(mp + 4);
      float v[8] = {wa.x*ma.x, wa.y*ma.y, wa.z*ma.z, wa.w*ma.w,
                    wb.x*mb.x, wb.y*mb.y, wb.z*mb.z, wb.w*mb.w};
      bf16x8 hv, lv;
#pragma unroll
      for (int j = 0; j < 8; ++j) { short h, lo2; split2(v[j], h, lo2); hv[j] = h; lv[j] = lo2; }
      bhi[ks] = hv; blo[ks] = lv;
    }
  }

  const size_t Tbase = (size_t)blockIdx.x * (NT * 32);

  // per-lane DMA source: lane covers floats [l*4, l*4+4) of a row's K=256
  const float* xsrc = (l < 32) ? (x0 + l * 4) : (x1 + (l - 32) * 4);

#define ISSUE(ts, r)                                                        \
  {                                                                         \
    _Pragma("unroll")                                                       \
    for (int i = 0; i < 4; ++i) {                                           \
      const int row = w * 4 + i;                                            \
      const size_t grow = Tbase + (size_t)(ts) * 32 + row;                  \
      gll16(xsrc + grow * 128, L + (r) * 32768 + row * 1024);               \
    }                                                                       \
  }

  // SPLIT: F[rr] fp32 (own 4 rows, granule-interleaved) -> B16[rr] hi/lo
#define SPLIT(rr)                                                           \
  {                                                                         \
    const int rowS = w * 4 + (l >> 4);                                      \
    const int v    = l & 15;                                                \
    const char* Fb = L + (rr) * 32768 + rowS * 1024;                        \
    char* Bh = L + 65536 + (rr) * 32768 + rowS * 512;                       \
    _Pragma("unroll")                                                       \
    for (int q = 0; q < 4; ++q) {                                           \
      const int g = v + 16 * q;            /* granule: floats [4g,4g+4) */  \
      float4 fv = *(const float4*)(Fb + g * 16);                            \
      short h0,h1,h2,h3, e0,e1,e2,e3;                                       \
      split2(fv.x, h0, e0); split2(fv.y, h1, e1);                           \
      split2(fv.z, h2, e2); split2(fv.w, h3, e3);                           \
      u32x2 hv, lv;                                                         \
      hv[0] = (unsigned short)h0 | ((unsigned)(unsigned short)h1 << 16);    \
      hv[1] = (unsigned short)h2 | ((unsigned)(unsigned short)h3 << 16);    \
      lv[0] = (unsigned short)e0 | ((unsigned)(unsigned short)e1 << 16);    \
      lv[1] = (unsigned short)e2 | ((unsigned)(unsigned short)e3 << 16);    \
      const int ks = g >> 3, qq = (g & 7) >> 1, h = g & 1;                  \
      const int off = ((ks * 64 + qq * 16) ^ ((rowS & 7) << 4)) + h * 8;    \
      *(u32x2*)(Bh + off)         = hv;                                     \
      *(u32x2*)(Bh + off + 16384) = lv;                                     \
    }                                                                       \
  }

  // ---------- prologue ----------
  ISSUE(0, 0);
  ISSUE(1, 1);
  asm volatile("s_waitcnt vmcnt(4)" ::: "memory");   // tile 0 landed (own rows)
  SPLIT(0);
  asm volatile("s_waitcnt lgkmcnt(0)" ::: "memory");
  __builtin_amdgcn_s_barrier();
  asm volatile("" ::: "memory");

  for (int tt = 0; tt < NT; ++tt) {
    const int r = tt & 1;

    // 1) issue tile tt+2 into F[r] (freed: SPLIT(tt) read it last iter)
    { const int ts = (tt + 2 < NT) ? (tt + 2) : (NT - 1); ISSUE(ts, r); }

    // 2) tile tt+1 landed (own rows); tt+2 stays in flight — never vmcnt(0)
    asm volatile("s_waitcnt vmcnt(4)" ::: "memory");

    // 3) merged region: SPLIT(tt+1) || MFMA(tt) || stores(tt)
    if (tt + 1 < NT) SPLIT(r ^ 1);

    f32x4 acc[2];
    acc[0] = (f32x4){0.f, 0.f, 0.f, 0.f};
    acc[1] = (f32x4){0.f, 0.f, 0.f, 0.f};
    {
      const char* Bb = L + 65536 + r * 32768;
#pragma unroll
      for (int ks = 0; ks < 8; ++ks) {
#pragma unroll
        for (int rt = 0; rt < 2; ++rt) {
          const int rl  = rt * 16 + l16;
          const int off = rl * 512 + ((ks * 64 + lq * 16) ^ ((rl & 7) << 4));
          bf16x8 xh = *(const bf16x8*)(Bb + off);
          bf16x8 xl = *(const bf16x8*)(Bb + off + 16384);
          // W ~ bhi+blo, X ~ xh+xl: 3 terms (drop blo*xl ~2^-30)
          acc[rt] = __builtin_amdgcn_mfma_f32_16x16x32_bf16(bhi[ks], xh, acc[rt], 0, 0, 0);
          acc[rt] = __builtin_amdgcn_mfma_f32_16x16x32_bf16(bhi[ks], xl, acc[rt], 0, 0, 0);
          acc[rt] = __builtin_amdgcn_mfma_f32_16x16x32_bf16(blo[ks], xh, acc[rt], 0, 0, 0);
        }
      }
    }

    // D (R13-verified): col(l16) = batch row, lq*4+r = out col -> f32x4
#pragma unroll
    for (int rt = 0; rt < 2; ++rt) {
      const size_t row = Tbase + (size_t)tt * 32 + rt * 16 + l16;
      *(f32x4*)&out[row * DOUT + w * 16 + lq * 4] = acc[rt];
    }

    // 4) single barrier: ds ops drained; global loads (tt+2) stay in flight
    asm volatile("s_waitcnt lgkmcnt(0)" ::: "memory");
    __builtin_amdgcn_s_barrier();
    asm volatile("" ::: "memory");
  }
#undef ISSUE
#undef SPLIT
}

extern "C" void kernel_launch(void* const* d_in, const int* in_sizes, int n_in,
                              void* d_out, int out_size, void* d_ws, size_t ws_size,
                              hipStream_t stream) {
  const float* x0 = (const float*)d_in[0];
  const float* x1 = (const float*)d_in[1];
  const float* w0 = (const float*)d_in[2];
  const float* w1 = (const float*)d_in[3];
  const float* m0 = (const float*)d_in[4];
  const float* m1 = (const float*)d_in[5];
  dagmm<<<NBLK, NTHR, 0, stream>>>(x0, x1, w0, w1, m0, m1, (float*)d_out);
}